// Round 2
// 391.908 us; speedup vs baseline: 1.0589x; 1.0589x over previous
//
#include <hip/hip_runtime.h>
#include <hip/hip_bf16.h>

// Problem constants (fixed by the reference setup)
#define E_EDGES 100000
#define KMAXN   16
#define D_EDGE  128
#define D_SBF   32
#define D_QUAD  32
#define NTILES  6250   // E_EDGES / 16, exact

typedef __bf16 bf16x8 __attribute__((ext_vector_type(8)));
typedef float  f32x4  __attribute__((ext_vector_type(4)));

__device__ __forceinline__ float silu_f(float x) {
    return x / (1.0f + __expf(-x));
}

// ---------------------------------------------------------------------------
// K012: fused  ssum (k0) -> m = silu(m_st@W_down) (k1) -> bilinear (k2).
//
// One wave owns one 16-edge tile end-to-end. The ssum and m tiles that
// previously round-tripped through HBM (12.8 MB write + 12.8 MB read each)
// now live in 2 KB per-wave LDS scratch:
//   - phase A: stream sbf tile (32 KB, same 8x128B-per-edge coalescing as
//     the old k0) and reduce over k into Sw[16][32].
//   - phase B: k1's MFMA from global m_st; epilogue writes silu(m) into
//     Mw[16][32] — the LDS store/load pair performs the (edge,q) transpose
//     the old pipeline did via HBM.
//   - phase C: k2's 32-step MFMA loop; A-frag built from Sw row + Mw row,
//     B from the block-shared W_bil LDS image (B-frag reads are contiguous
//     256B/quad -> bank-uniform, no conflicts).
// Wave-synchronous producer/consumer: per-wave buffers, same wave writes
// and reads them, DS pipe is in-order; one s_waitcnt lgkmcnt(0) per tile
// as a compiler/HW ordering fence. No __syncthreads in the loop (waves
// have different trip counts).
// LDS: 64 KB W_bil + 4 waves * (2+2) KB = 80 KB -> 2 blocks/CU (unchanged
// vs the previous 64 KB version's occupancy).
// ---------------------------------------------------------------------------
__global__ __launch_bounds__(256) void k012_fused(
        const float* __restrict__ sbf,
        const float* __restrict__ m_st,
        const float* __restrict__ W_down,
        const float* __restrict__ W_bil,
        const float* __restrict__ scale_sbf,
        float* __restrict__ ws_x)
{
    __shared__ __align__(16) __bf16 Blds[32768];     // 64 KB W_bil (bf16)
    __shared__ __align__(16) float  Slds[4][512];    // per-wave ssum tile 16x32
    __shared__ __align__(16) float  Mlds[4][512];    // per-wave m tile 16x32

    // Stage W_bil (coalesced read: i = q*1024 + s*32 + o) into
    // Blds[((s*4 + q/8)*32 + o)*8 + (q&7)]  (B-frag-contiguous order)
    for (int i = threadIdx.x; i < 32768; i += 256) {
        const int q = i >> 10;
        const int rem = i & 1023;
        const int s = rem >> 5;
        const int o = rem & 31;
        Blds[(((s << 2) + (q >> 3)) * 32 + o) * 8 + (q & 7)] = (__bf16)W_bil[i];
    }

    const int lane = threadIdx.x & 63;
    const int n15  = lane & 15;
    const int quad = lane >> 4;
    const int wid  = threadIdx.x >> 6;
    const int wave = blockIdx.x * 4 + wid;
    const int nwav = gridDim.x * 4;
    const int e8   = lane >> 3;   // 0..7  edge within half-tile (phase A)
    const int c    = lane & 7;    // 0..7  float4 column group   (phase A)

    // W_down B-fragments: B[k=kk*32+quad*8+j][n = nt*16 + n15]
    bf16x8 bdf[4][2];
    #pragma unroll
    for (int kk = 0; kk < 4; kk++) {
        #pragma unroll
        for (int nt = 0; nt < 2; nt++) {
            bf16x8 b;
            #pragma unroll
            for (int j = 0; j < 8; j++)
                b[j] = (__bf16)W_down[(kk*32 + quad*8 + j) * 32 + nt*16 + n15];
            bdf[kk][nt] = b;
        }
    }

    __syncthreads();   // W_bil image ready (only cross-wave dependency)

    const float scale = scale_sbf[0];
    float* Sw = Slds[wid];
    float* Mw = Mlds[wid];
    const bf16x8* Bq = (const bf16x8*)Blds;  // unit = 8 bf16

    for (int tile = wave; tile < NTILES; tile += nwav) {
        const int eb = tile * 16;

        // ---- phase A: ssum tile -> Sw[16][32] (contiguous 1KB b128 writes)
        #pragma unroll
        for (int eh = 0; eh < 2; eh++) {
            const float* p = sbf + (size_t)(eb + eh*8 + e8) * (KMAXN * D_SBF) + c * 4;
            float ax = 0.f, ay = 0.f, az = 0.f, aw = 0.f;
            #pragma unroll
            for (int k = 0; k < KMAXN; k++) {
                float4 v = *(const float4*)(p + k * D_SBF);
                ax += v.x; ay += v.y; az += v.z; aw += v.w;
            }
            float4 r = {ax, ay, az, aw};
            *(float4*)(Sw + (eh*8 + e8)*32 + c*4) = r;
        }

        // ---- phase B: m = silu(m_st @ W_down) for this tile -> Mw[16][32]
        // A layout: A[m=lane&15][k=quad*8+j]; C: col=lane&15, row=quad*4+reg.
        const float* arow = m_st + (size_t)(eb + n15) * 128 + quad * 8;
        f32x4 acc0 = {0.f, 0.f, 0.f, 0.f};
        f32x4 acc1 = {0.f, 0.f, 0.f, 0.f};
        #pragma unroll
        for (int kk = 0; kk < 4; kk++) {
            float4 p0 = *(const float4*)(arow + kk*32);
            float4 p1 = *(const float4*)(arow + kk*32 + 4);
            bf16x8 a;
            a[0]=(__bf16)p0.x; a[1]=(__bf16)p0.y; a[2]=(__bf16)p0.z; a[3]=(__bf16)p0.w;
            a[4]=(__bf16)p1.x; a[5]=(__bf16)p1.y; a[6]=(__bf16)p1.z; a[7]=(__bf16)p1.w;
            acc0 = __builtin_amdgcn_mfma_f32_16x16x32_bf16(a, bdf[kk][0], acc0, 0, 0, 0);
            acc1 = __builtin_amdgcn_mfma_f32_16x16x32_bf16(a, bdf[kk][1], acc1, 0, 0, 0);
        }
        #pragma unroll
        for (int reg = 0; reg < 4; reg++) {
            Mw[(quad*4 + reg)*32 +      n15] = silu_f(acc0[reg]);
            Mw[(quad*4 + reg)*32 + 16 + n15] = silu_f(acc1[reg]);
        }

        // Fence: all per-wave LDS writes (Sw, Mw) complete before cross-lane
        // reads below. DS pipe is in-order per wave; this also blocks any
        // compiler reordering across the producer/consumer boundary.
        asm volatile("s_waitcnt lgkmcnt(0)" ::: "memory");

        // ---- phase C: x = scale * sum_{s,q} ssum[e,s]*m[e,q]*W_bil[q,s,o]
        const float* mrow = Mw + n15*32 + quad*8;
        float4 m0 = *(const float4*)mrow;
        float4 m1 = *(const float4*)(mrow + 4);
        float mj[8] = {m0.x, m0.y, m0.z, m0.w, m1.x, m1.y, m1.z, m1.w};

        float ss[32];
        const float* srow = Sw + n15*32;
        #pragma unroll
        for (int cc = 0; cc < 8; cc++) {
            float4 v = *(const float4*)(srow + cc*4);
            ss[cc*4+0] = v.x; ss[cc*4+1] = v.y; ss[cc*4+2] = v.z; ss[cc*4+3] = v.w;
        }

        f32x4 xc0 = {0.f, 0.f, 0.f, 0.f};
        f32x4 xc1 = {0.f, 0.f, 0.f, 0.f};
        #pragma unroll
        for (int kk = 0; kk < 32; kk++) {
            const float sv = ss[kk];
            bf16x8 a;
            #pragma unroll
            for (int j = 0; j < 8; j++) a[j] = (__bf16)(sv * mj[j]);
            bf16x8 b0 = Bq[(kk*4 + quad)*32 +      n15];
            bf16x8 b1 = Bq[(kk*4 + quad)*32 + 16 + n15];
            xc0 = __builtin_amdgcn_mfma_f32_16x16x32_bf16(a, b0, xc0, 0, 0, 0);
            xc1 = __builtin_amdgcn_mfma_f32_16x16x32_bf16(a, b1, xc1, 0, 0, 0);
        }

        #pragma unroll
        for (int reg = 0; reg < 4; reg++) {
            const int eo = eb + quad*4 + reg;
            ws_x[(size_t)eo*32 +      n15] = xc0[reg] * scale;
            ws_x[(size_t)eo*32 + 16 + n15] = xc1[reg] * scale;
        }
        // Next iteration's Sw/Mw writes are after these reads in program
        // order; in-order DS + the per-tile fence keep WAR safe.
    }
}

// ---------------------------------------------------------------------------
// K3: out[e] = (silu(x[e]@W_up_st) + silu(x[idx_swap[e]]@W_up_ts)) * 1/sqrt(2)
// K=32 -> one K-step, N=128 -> 8 N-tiles. Both B matrices live in registers.
// Unchanged from the 411 µs harness-verified version (the gather forces the
// ws_x materialization; fusing it would need a grid-wide sync for ~2 µs).
// ---------------------------------------------------------------------------
__global__ __launch_bounds__(256) void k3_up(
        const float* __restrict__ ws_x,
        const int*   __restrict__ idx_swap,
        const float* __restrict__ W_up_st,
        const float* __restrict__ W_up_ts,
        float* __restrict__ out)
{
    const int lane = threadIdx.x & 63;
    const int n15  = lane & 15;
    const int quad = lane >> 4;
    const int wave = blockIdx.x * 4 + (threadIdx.x >> 6);
    const int nwav = gridDim.x * 4;

    bf16x8 bst[8], bts[8];
    #pragma unroll
    for (int nt = 0; nt < 8; nt++) {
        bf16x8 a, b;
        #pragma unroll
        for (int j = 0; j < 8; j++) {
            a[j] = (__bf16)W_up_st[(quad*8 + j) * 128 + nt*16 + n15];
            b[j] = (__bf16)W_up_ts[(quad*8 + j) * 128 + nt*16 + n15];
        }
        bst[nt] = a; bts[nt] = b;
    }

    const float cinv = 0.70710678118654752440f;

    for (int tile = wave; tile < NTILES; tile += nwav) {
        const int eb = tile * 16;
        const int e  = eb + n15;
        const int esw = idx_swap[e];

        const float* xr = ws_x + (size_t)e   * 32 + quad * 8;
        const float* xs = ws_x + (size_t)esw * 32 + quad * 8;
        float4 r0 = *(const float4*)xr, r1 = *(const float4*)(xr + 4);
        float4 s0 = *(const float4*)xs, s1 = *(const float4*)(xs + 4);

        bf16x8 ast, ats;
        ast[0]=(__bf16)r0.x; ast[1]=(__bf16)r0.y; ast[2]=(__bf16)r0.z; ast[3]=(__bf16)r0.w;
        ast[4]=(__bf16)r1.x; ast[5]=(__bf16)r1.y; ast[6]=(__bf16)r1.z; ast[7]=(__bf16)r1.w;
        ats[0]=(__bf16)s0.x; ats[1]=(__bf16)s0.y; ats[2]=(__bf16)s0.z; ats[3]=(__bf16)s0.w;
        ats[4]=(__bf16)s1.x; ats[5]=(__bf16)s1.y; ats[6]=(__bf16)s1.z; ats[7]=(__bf16)s1.w;

        f32x4 accst[8], accts[8];
        #pragma unroll
        for (int nt = 0; nt < 8; nt++) {
            f32x4 z = {0.f, 0.f, 0.f, 0.f};
            accst[nt] = __builtin_amdgcn_mfma_f32_16x16x32_bf16(ast, bst[nt], z, 0, 0, 0);
            accts[nt] = __builtin_amdgcn_mfma_f32_16x16x32_bf16(ats, bts[nt], z, 0, 0, 0);
        }

        #pragma unroll
        for (int nt = 0; nt < 8; nt++) {
            #pragma unroll
            for (int reg = 0; reg < 4; reg++) {
                const int eo = eb + quad*4 + reg;
                out[(size_t)eo * 128 + nt*16 + n15] =
                    (silu_f(accst[nt][reg]) + silu_f(accts[nt][reg])) * cinv;
            }
        }
    }
}

// ---------------------------------------------------------------------------
extern "C" void kernel_launch(void* const* d_in, const int* in_sizes, int n_in,
                              void* d_out, int out_size, void* d_ws, size_t ws_size,
                              hipStream_t stream)
{
    const float* m_st      = (const float*)d_in[0];
    const float* sbf       = (const float*)d_in[1];
    const int*   idx_swap  = (const int*)  d_in[2];
    // d_in[3] edge_nb_idx, d_in[4] edge_nb_ragged_idx: dense trivial structure
    const float* W_down    = (const float*)d_in[5];
    const float* W_bil     = (const float*)d_in[6];
    const float* W_up_st   = (const float*)d_in[7];
    const float* W_up_ts   = (const float*)d_in[8];
    const float* scale_sbf = (const float*)d_in[9];
    float* out = (float*)d_out;

    // Only intermediate left: x (E,32) f32 = 12.8 MB. ssum/ws_m are fused away.
    float* ws_x = (float*)d_ws;

    // 512 blocks * 4 waves, 2 blocks/CU resident (80 KB LDS) -> whole grid
    // co-resident, ~3 tiles per wave.
    hipLaunchKernelGGL(k012_fused, dim3(512),  dim3(256), 0, stream,
                       sbf, m_st, W_down, W_bil, scale_sbf, ws_x);
    hipLaunchKernelGGL(k3_up,      dim3(1024), dim3(256), 0, stream,
                       ws_x, idx_swap, W_up_st, W_up_ts, out);
}

// Round 3
// 383.527 us; speedup vs baseline: 1.0820x; 1.0219x over previous
//
#include <hip/hip_runtime.h>
#include <hip/hip_bf16.h>

// Problem constants (fixed by the reference setup)
#define E_EDGES 100000
#define KMAXN   16
#define D_EDGE  128
#define D_SBF   32
#define D_QUAD  32
#define NTILES  6250   // E_EDGES / 16, exact
#define SP      36     // padded LDS row stride (floats): 16B-aligned, breaks
                       // the stride-128B bank pattern (16-way -> 2-way)

typedef __bf16 bf16x8 __attribute__((ext_vector_type(8)));
typedef float  f32x4  __attribute__((ext_vector_type(4)));

__device__ __forceinline__ float silu_f(float x) {
    return x / (1.0f + __expf(-x));
}

// ---------------------------------------------------------------------------
// KPREP: one-time weight repack (f32 -> bf16, MFMA B-fragment order, global).
//   Wb16: W_bil  (32,32,32) -> 4096 units of bf16x8; unit u=(s*4+q/8)*32+o,
//         element q&7  (identical ordering to the old LDS image).
//   Wd16: W_down (128,32)   -> 512 units; unit (kk*2+nt)*64+quad*16+n15,
//         element j = W_down[(kk*32+quad*8+j)*32 + nt*16 + n15].
// Both images are tiny (64KB + 8KB) and stay L2-resident for k012.
// ---------------------------------------------------------------------------
__global__ __launch_bounds__(256) void kprep(
        const float* __restrict__ W_down,
        const float* __restrict__ W_bil,
        __bf16* __restrict__ Wd16,
        __bf16* __restrict__ Wb16)
{
    const int t = blockIdx.x * 256 + threadIdx.x;
    if (t < 4096) {                       // W_bil unit
        const int o   = t & 31;
        const int tmp = t >> 5;           // s*4 + qh
        const int qh  = tmp & 3;
        const int s   = tmp >> 2;
        bf16x8 u;
        #pragma unroll
        for (int ql = 0; ql < 8; ql++)
            u[ql] = (__bf16)W_bil[(qh*8 + ql)*1024 + s*32 + o];
        *(bf16x8*)(Wb16 + (size_t)t * 8) = u;
    } else if (t < 4096 + 512) {          // W_down unit
        const int t2   = t - 4096;
        const int n15  = t2 & 15;
        const int quad = (t2 >> 4) & 3;
        const int nt   = (t2 >> 6) & 1;
        const int kk   = t2 >> 7;
        bf16x8 u;
        #pragma unroll
        for (int j = 0; j < 8; j++)
            u[j] = (__bf16)W_down[(kk*32 + quad*8 + j)*32 + nt*16 + n15];
        *(bf16x8*)(Wd16 + (size_t)t2 * 8) = u;
    }
}

// ---------------------------------------------------------------------------
// K012 v2: fused ssum -> silu(m_st@W_down) -> bilinear. Same math as the
// verified v1, restructured for memory-level parallelism:
//   - W_bil/W_down fragments come from the global bf16 images (L2-resident,
//     coalesced 16B/lane dwordx4) instead of a 64KB LDS stage. LDS drops
//     80KB -> 18KB; no __syncthreads at all.
//   - __launch_bounds__(256,4): cap 128 VGPR -> 4 waves/SIMD, 16 waves/CU
//     (2x the v1 occupancy) so phase-A HBM bursts from many waves overlap
//     the no-memory phase C of others.
//   - exactly ONE 16-edge tile per wave, 1563 blocks: perfect balance
//     (v1's 4-vs-3 tiles/wave tail was +31% on the critical wave).
//   - Sw/Mw rows padded to 36 floats: phase-C row reads 16-way -> 2-way.
// ---------------------------------------------------------------------------
__global__ __launch_bounds__(256, 4) void k012_fused(
        const float* __restrict__ sbf,
        const float* __restrict__ m_st,
        const __bf16* __restrict__ Wd16,
        const __bf16* __restrict__ Wb16,
        const float* __restrict__ scale_sbf,
        float* __restrict__ ws_x)
{
    __shared__ __align__(16) float Slds[4][16 * SP];   // 2304 B / wave
    __shared__ __align__(16) float Mlds[4][16 * SP];   // 2304 B / wave

    const int lane = threadIdx.x & 63;
    const int n15  = lane & 15;
    const int quad = lane >> 4;
    const int wid  = threadIdx.x >> 6;
    const int tile = blockIdx.x * 4 + wid;
    if (tile >= NTILES) return;            // no barriers anywhere -> safe
    const int eb = tile * 16;
    const int e8 = lane >> 3;              // 0..7 edge within half-tile
    const int c  = lane & 7;               // 0..7 float4 column group

    float* Sw = Slds[wid];
    float* Mw = Mlds[wid];

    // ---- phase A: ssum tile -> Sw[16][SP]
    #pragma unroll
    for (int eh = 0; eh < 2; eh++) {
        const float* p = sbf + (size_t)(eb + eh*8 + e8) * (KMAXN * D_SBF) + c * 4;
        float ax = 0.f, ay = 0.f, az = 0.f, aw = 0.f;
        #pragma unroll
        for (int k = 0; k < KMAXN; k++) {
            float4 v = *(const float4*)(p + k * D_SBF);
            ax += v.x; ay += v.y; az += v.z; aw += v.w;
        }
        float4 r = {ax, ay, az, aw};
        *(float4*)(Sw + (eh*8 + e8) * SP + c * 4) = r;
    }

    // ---- phase B: m = silu(m_st @ W_down) -> Mw[16][SP]
    // A layout: A[m=lane&15][k=quad*8+j]; C: col=lane&15, row=quad*4+reg.
    // B-frags loaded inline from the global bf16 image (transient regs).
    const bf16x8* Wdq = (const bf16x8*)Wd16;
    const float* arow = m_st + (size_t)(eb + n15) * 128 + quad * 8;
    f32x4 acc0 = {0.f, 0.f, 0.f, 0.f};
    f32x4 acc1 = {0.f, 0.f, 0.f, 0.f};
    #pragma unroll
    for (int kk = 0; kk < 4; kk++) {
        float4 p0 = *(const float4*)(arow + kk*32);
        float4 p1 = *(const float4*)(arow + kk*32 + 4);
        bf16x8 a;
        a[0]=(__bf16)p0.x; a[1]=(__bf16)p0.y; a[2]=(__bf16)p0.z; a[3]=(__bf16)p0.w;
        a[4]=(__bf16)p1.x; a[5]=(__bf16)p1.y; a[6]=(__bf16)p1.z; a[7]=(__bf16)p1.w;
        bf16x8 b0 = Wdq[(kk*2 + 0)*64 + quad*16 + n15];
        bf16x8 b1 = Wdq[(kk*2 + 1)*64 + quad*16 + n15];
        acc0 = __builtin_amdgcn_mfma_f32_16x16x32_bf16(a, b0, acc0, 0, 0, 0);
        acc1 = __builtin_amdgcn_mfma_f32_16x16x32_bf16(a, b1, acc1, 0, 0, 0);
    }
    #pragma unroll
    for (int reg = 0; reg < 4; reg++) {
        Mw[(quad*4 + reg)*SP +      n15] = silu_f(acc0[reg]);
        Mw[(quad*4 + reg)*SP + 16 + n15] = silu_f(acc1[reg]);
    }

    // Fence: per-wave LDS producer/consumer boundary (cross-lane reads next).
    // DS pipe is in-order per wave; the clobber stops compiler reordering.
    asm volatile("s_waitcnt lgkmcnt(0)" ::: "memory");

    // ---- phase C: x = scale * sum_{s,q} ssum[e,s]*m[e,q]*W_bil[q,s,o]
    // A-frag: A[e=n15][q=quad*8+j] = ss[e][kk] * m[e][quad*8+j].
    const float* mrow = Mw + n15*SP + quad*8;
    float4 m0 = *(const float4*)mrow;
    float4 m1 = *(const float4*)(mrow + 4);
    float mj[8] = {m0.x, m0.y, m0.z, m0.w, m1.x, m1.y, m1.z, m1.w};
    const float* srow = Sw + n15*SP;       // padded: 2-way banks, broadcast/quad
    const bf16x8* Bq = (const bf16x8*)Wb16;

    f32x4 xc0 = {0.f, 0.f, 0.f, 0.f};
    f32x4 xc1 = {0.f, 0.f, 0.f, 0.f};
    #pragma unroll
    for (int kk = 0; kk < 32; kk++) {
        const float sv = srow[kk];
        bf16x8 a;
        #pragma unroll
        for (int j = 0; j < 8; j++) a[j] = (__bf16)(sv * mj[j]);
        bf16x8 b0 = Bq[(kk*4 + quad)*32 +      n15];
        bf16x8 b1 = Bq[(kk*4 + quad)*32 + 16 + n15];
        xc0 = __builtin_amdgcn_mfma_f32_16x16x32_bf16(a, b0, xc0, 0, 0, 0);
        xc1 = __builtin_amdgcn_mfma_f32_16x16x32_bf16(a, b1, xc1, 0, 0, 0);
    }

    const float scale = scale_sbf[0];
    #pragma unroll
    for (int reg = 0; reg < 4; reg++) {
        const int eo = eb + quad*4 + reg;
        ws_x[(size_t)eo*32 +      n15] = xc0[reg] * scale;
        ws_x[(size_t)eo*32 + 16 + n15] = xc1[reg] * scale;
    }
}

// ---------------------------------------------------------------------------
// K3: out[e] = (silu(x[e]@W_up_st) + silu(x[idx_swap[e]]@W_up_ts)) / sqrt(2)
// Unchanged from the harness-verified version.
// ---------------------------------------------------------------------------
__global__ __launch_bounds__(256) void k3_up(
        const float* __restrict__ ws_x,
        const int*   __restrict__ idx_swap,
        const float* __restrict__ W_up_st,
        const float* __restrict__ W_up_ts,
        float* __restrict__ out)
{
    const int lane = threadIdx.x & 63;
    const int n15  = lane & 15;
    const int quad = lane >> 4;
    const int wave = blockIdx.x * 4 + (threadIdx.x >> 6);
    const int nwav = gridDim.x * 4;

    bf16x8 bst[8], bts[8];
    #pragma unroll
    for (int nt = 0; nt < 8; nt++) {
        bf16x8 a, b;
        #pragma unroll
        for (int j = 0; j < 8; j++) {
            a[j] = (__bf16)W_up_st[(quad*8 + j) * 128 + nt*16 + n15];
            b[j] = (__bf16)W_up_ts[(quad*8 + j) * 128 + nt*16 + n15];
        }
        bst[nt] = a; bts[nt] = b;
    }

    const float cinv = 0.70710678118654752440f;

    for (int tile = wave; tile < NTILES; tile += nwav) {
        const int eb = tile * 16;
        const int e  = eb + n15;
        const int esw = idx_swap[e];

        const float* xr = ws_x + (size_t)e   * 32 + quad * 8;
        const float* xs = ws_x + (size_t)esw * 32 + quad * 8;
        float4 r0 = *(const float4*)xr, r1 = *(const float4*)(xr + 4);
        float4 s0 = *(const float4*)xs, s1 = *(const float4*)(xs + 4);

        bf16x8 ast, ats;
        ast[0]=(__bf16)r0.x; ast[1]=(__bf16)r0.y; ast[2]=(__bf16)r0.z; ast[3]=(__bf16)r0.w;
        ast[4]=(__bf16)r1.x; ast[5]=(__bf16)r1.y; ast[6]=(__bf16)r1.z; ast[7]=(__bf16)r1.w;
        ats[0]=(__bf16)s0.x; ats[1]=(__bf16)s0.y; ats[2]=(__bf16)s0.z; ats[3]=(__bf16)s0.w;
        ats[4]=(__bf16)s1.x; ats[5]=(__bf16)s1.y; ats[6]=(__bf16)s1.z; ats[7]=(__bf16)s1.w;

        f32x4 accst[8], accts[8];
        #pragma unroll
        for (int nt = 0; nt < 8; nt++) {
            f32x4 z = {0.f, 0.f, 0.f, 0.f};
            accst[nt] = __builtin_amdgcn_mfma_f32_16x16x32_bf16(ast, bst[nt], z, 0, 0, 0);
            accts[nt] = __builtin_amdgcn_mfma_f32_16x16x32_bf16(ats, bts[nt], z, 0, 0, 0);
        }

        #pragma unroll
        for (int nt = 0; nt < 8; nt++) {
            #pragma unroll
            for (int reg = 0; reg < 4; reg++) {
                const int eo = eb + quad*4 + reg;
                out[(size_t)eo * 128 + nt*16 + n15] =
                    (silu_f(accst[nt][reg]) + silu_f(accts[nt][reg])) * cinv;
            }
        }
    }
}

// ---------------------------------------------------------------------------
extern "C" void kernel_launch(void* const* d_in, const int* in_sizes, int n_in,
                              void* d_out, int out_size, void* d_ws, size_t ws_size,
                              hipStream_t stream)
{
    const float* m_st      = (const float*)d_in[0];
    const float* sbf       = (const float*)d_in[1];
    const int*   idx_swap  = (const int*)  d_in[2];
    // d_in[3] edge_nb_idx, d_in[4] edge_nb_ragged_idx: dense trivial structure
    const float* W_down    = (const float*)d_in[5];
    const float* W_bil     = (const float*)d_in[6];
    const float* W_up_st   = (const float*)d_in[7];
    const float* W_up_ts   = (const float*)d_in[8];
    const float* scale_sbf = (const float*)d_in[9];
    float* out = (float*)d_out;

    const size_t nEQ = (size_t)E_EDGES * D_QUAD;   // 3.2M floats
    float*  ws_x = (float*)d_ws;                   // 12.8 MB
    __bf16* Wd16 = (__bf16*)(ws_x + nEQ);          // 8 KB  (16B-aligned)
    __bf16* Wb16 = Wd16 + 512 * 8;                 // 64 KB (16B-aligned)

    hipLaunchKernelGGL(kprep,      dim3(18),   dim3(256), 0, stream,
                       W_down, W_bil, Wd16, Wb16);
    // 1563 blocks * 4 waves = 6252 wave-slots for 6250 tiles: 1 tile/wave.
    hipLaunchKernelGGL(k012_fused, dim3(1563), dim3(256), 0, stream,
                       sbf, m_st, Wd16, Wb16, scale_sbf, ws_x);
    hipLaunchKernelGGL(k3_up,      dim3(1024), dim3(256), 0, stream,
                       ws_x, idx_swap, W_up_st, W_up_ts, out);
}